// Round 2
// baseline (384.711 us; speedup 1.0000x reference)
//
#include <hip/hip_runtime.h>
#include <math.h>

#define W    3072
#define HH   3072
#define HOUT 3060       // HH - 12 (valid conv output for 13x13 kernel)
#define TW   64         // output cols per block
#define TH   56         // output rows per block (4 waves x 14 rows)
#define XR   68         // xt rows = TH + 12
#define XTS  76         // xt col stride (even -> b64-aligned col-pair reads)
#define VTS  77         // vt col stride (odd -> scalar reads/writes conflict-free)
#define VTW  (14*VTS)   // per-wave vt words = 1078

typedef float f2 __attribute__((ext_vector_type(2)));

// pair tables: p[j] = {tap[j], tap[j-1]} (0-padded at the ends) so one packed
// FMA updates output cols (2jj, 2jj+1) / keeps per-output accumulation order
// identical to the scalar version (the zero-tap halves add +/-0 only).
struct HessTaps {
  f2 pa[14], pbb[14], pm[14], pn[14];   // H-pass pair tables
  float a[13], bb[13], m[13], n[13];    // V-pass scalar taps
};

__device__ __forceinline__ f2 pk_fma(f2 a, f2 b, f2 c) {
#if defined(__has_builtin) && __has_builtin(__builtin_elementwise_fma)
  return __builtin_elementwise_fma(a, b, c);   // -> v_pk_fma_f32
#else
  f2 r; r.x = fmaf(a.x, b.x, c.x); r.y = fmaf(a.y, b.y, c.y); return r;
#endif
}

// ---- per-block reduction -> one f64 atomic ---------------------------------
__device__ __forceinline__ void reduce_add(float v, double* acc) {
  __shared__ float red[8];
  #pragma unroll
  for (int o = 32; o > 0; o >>= 1) v += __shfl_down(v, o, 64);
  int lane = threadIdx.x & 63, wid = threadIdx.x >> 6;
  if (lane == 0) red[wid] = v;
  __syncthreads();
  if (threadIdx.x == 0) {
    float s = 0.f;
    int nw = (blockDim.x + 63) >> 6;
    for (int i = 0; i < nw; ++i) s += red[i];
    unsafeAtomicAdd(acc, (double)s);
  }
  __syncthreads();   // protect red[] for a subsequent call
}

// ---- Hessian + TV + folded gf/mse, both images via gridDim.z ---------------
// 64x56 output tile, 4 waves x 14 rows each, wave-local V->H (no inter-term
// barriers; same-wave LDS RAW is ordered by lgkmcnt the compiler inserts).
//  * V pass: lane p<38 owns col-pair (2p,2p+1); ds_read_b64 from xt
//    (even stride 76, <=3-way on reads); 14 packed accumulators cover the
//    wave's 14 rows; one chain covers all 76 cols -> NO halo chain.
//    Writes are SCALAR into vt stride 77 (lane word-stride 2 -> 2/bank, free).
//  * H pass: lane (row r14<14, colgroup cg) slides 28 SCALAR reads at
//    stride-1 (stride-77 rows -> <=2/bank, free); 8 packed col-pair
//    accumulators with host-precomputed tap pairs; 112 pk FMAs vs 208 scalar.
// LDS: xt 68*76*4=20672 + vt 4*1078*4=17248 + red 32 = 37952 B -> 4 blocks/CU.
__global__ __launch_bounds__(256, 4) void hess_kernel(const float* __restrict__ Gnn,
                                                      const float* __restrict__ Lr,
                                                      const float* __restrict__ T,
                                                      const float* __restrict__ Xr,
                                                      const float* __restrict__ St,
                                                      const float* __restrict__ Mp,
                                                      double* acc, HessTaps tp) {
  __shared__ float xt[XR * XTS];
  __shared__ float vt[4 * VTW];
  const float* img = (blockIdx.z == 0) ? Gnn : Lr;
  int oy = blockIdx.y * TH, ox = blockIdx.x * TW;
  int t = threadIdx.x;
  int wv = t >> 6, ln = t & 63;    // wave id 0..3, lane 0..63

  // load xt (68 rows x 76 cols) as aligned float4 with edge masking
  for (int idx = t; idx < XR * 19; idx += 256) {
    int r = idx / 19, g = idx - r * 19;
    int gr = oy + r, gc = ox + 4 * g;
    float4 v = {0.f, 0.f, 0.f, 0.f};
    if (gr < HH) {
      const float* p = &img[(size_t)gr * W + gc];
      if (gc + 3 < W) v = *(const float4*)p;
      else {
        if (gc < W)     v.x = p[0];
        if (gc + 1 < W) v.y = p[1];
        if (gc + 2 < W) v.z = p[2];
      }
    }
    *(float4*)&xt[r * XTS + 4 * g] = v;
  }
  __syncthreads();

  float tvl = 0.f;   // TV accumulator
  float hl  = 0.f;   // Hessian accumulator

  // TV Dx term on x: |x(r,c) - x(r,c+1)|  (lanes contiguous -> free)
  {
    int gc = ox + ln;
    if (gc < W - 1) {
      #pragma unroll
      for (int i = 0; i < 14; ++i) {
        int r = wv * 14 + i;
        if (oy + r < HH)
          tvl += fabsf(xt[r * XTS + ln] - xt[r * XTS + ln + 1]);
      }
    }
  }

  // ---- V pass: packed over col-pairs; wave-local rows 14wv..14wv+13.
  // out row i needs xt rows (14wv+i)+0..12 -> window u in [0,26).
  #define VFIRST(TAP)                                                       \
    if (ln < 38) {                                                          \
      int r0 = wv * 14;                                                     \
      const float* xp = &xt[r0 * XTS + 2 * ln];                             \
      f2 o_[14];                                                            \
      _Pragma("unroll")                                                     \
      for (int i = 0; i < 14; ++i) o_[i] = (f2){0.f, 0.f};                  \
      _Pragma("unroll")                                                     \
      for (int u = 0; u < 26; ++u) {                                        \
        f2 xv = *(const f2*)(xp + u * XTS);                                 \
        _Pragma("unroll")                                                   \
        for (int i = 0; i < 14; ++i) {                                      \
          int kk = u - i;                                                   \
          if (kk >= 0 && kk <= 12) {                                        \
            float tv_ = (TAP)[kk];                                          \
            o_[i] = pk_fma((f2){tv_, tv_}, xv, o_[i]);                      \
          }                                                                 \
        }                                                                   \
      }                                                                     \
      float* vw = &vt[wv * VTW + 2 * ln];                                   \
      _Pragma("unroll")                                                     \
      for (int i = 0; i < 14; ++i) {                                        \
        vw[i * VTS]     = o_[i].x;   /* scalar: lane stride 2 -> free */    \
        vw[i * VTS + 1] = o_[i].y;                                          \
      }                                                                     \
    }

  // ---- H pass: packed over output col-pairs, scalar sliding reads of the
  // SAME wave's vt rows. lane = (r14 = ln&15 (<14), cg = ln>>4).
  #define HSECOND(PTAB, WGT)                                                \
    {                                                                       \
      int r14 = ln & 15, cg = ln >> 4;                                      \
      if (r14 < 14) {                                                       \
        const float* vrow = &vt[wv * VTW + r14 * VTS + cg * 16];            \
        f2 o_[8];                                                           \
        _Pragma("unroll")                                                   \
        for (int jj = 0; jj < 8; ++jj) o_[jj] = (f2){0.f, 0.f};             \
        _Pragma("unroll")                                                   \
        for (int j = 0; j < 28; ++j) {                                      \
          float v = vrow[j];                                                \
          f2 vv = {v, v};                                                   \
          _Pragma("unroll")                                                 \
          for (int jj = 0; jj < 8; ++jj) {                                  \
            int k2 = j - 2 * jj;                                            \
            if (k2 >= 0 && k2 <= 13)                                        \
              o_[jj] = pk_fma((PTAB)[k2], vv, o_[jj]);                      \
          }                                                                 \
        }                                                                   \
        int gr = oy + wv * 14 + r14;                                        \
        int gc0 = ox + cg * 16;                                             \
        float wr = (gr < HOUT) ? (WGT) : 0.f;                               \
        _Pragma("unroll")                                                   \
        for (int jj = 0; jj < 8; ++jj) {                                    \
          float m0 = (gc0 + 2 * jj     < HOUT) ? wr : 0.f;                  \
          float m1 = (gc0 + 2 * jj + 1 < HOUT) ? wr : 0.f;                  \
          hl = fmaf(m0, fabsf(o_[jj].x), hl);                               \
          hl = fmaf(m1, fabsf(o_[jj].y), hl);                               \
        }                                                                   \
      }                                                                     \
    }

  // term 1: conv(x, Gxx) = vert bb, horiz a    (no barrier between V and H)
  VFIRST(tp.bb);
  HSECOND(tp.pa, 1.0f);

  // d = x - target (in place); all waves must be done reading xt first
  __syncthreads();
  for (int idx = t; idx < XR * 19; idx += 256) {
    int r = idx / 19, g = idx - r * 19;
    int gr = oy + r, gc = ox + 4 * g;
    float4 v = {0.f, 0.f, 0.f, 0.f};
    if (gr < HH) {
      const float* p = &T[(size_t)gr * W + gc];
      if (gc + 3 < W) v = *(const float4*)p;
      else {
        if (gc < W)     v.x = p[0];
        if (gc + 1 < W) v.y = p[1];
        if (gc + 2 < W) v.z = p[2];
      }
    }
    float4 cur = *(float4*)&xt[r * XTS + 4 * g];
    cur.x -= v.x; cur.y -= v.y; cur.z -= v.z; cur.w -= v.w;
    *(float4*)&xt[r * XTS + 4 * g] = cur;
  }
  __syncthreads();

  // TV Dy term on d: |d(r,c) - d(r+1,c)|, r < HH-1
  {
    int gc = ox + ln;
    if (gc < W) {
      #pragma unroll
      for (int i = 0; i < 14; ++i) {
        int r = wv * 14 + i;
        if (oy + r < HH - 1)
          tvl += fabsf(xt[r * XTS + ln] - xt[(r + 1) * XTS + ln]);
      }
    }
  }

  // term 2: conv(d, Gyy) = vert a, horiz bb
  VFIRST(tp.a);
  HSECOND(tp.pbb, 1.0f);

  // term 3: conv(d, Gxy) = vert m, horiz n, weight 2 (isotropic)
  VFIRST(tp.m);
  HSECOND(tp.pn, 2.0f);

  // ---- folded gf term (gf(x,x)==x exactly -> sum|st-x|) + sampled L1*map.
  // hess is at ~8% HBM; these streaming reads overlap with conv compute and
  // save two dispatches. acc[0] and acc[2] both enter finalize with weight 1,
  // so both fold into acc[0].
  float gm = 0.f;
  {
    int bid = (blockIdx.z * gridDim.y + blockIdx.y) * gridDim.x + blockIdx.x;
    int nthr = gridDim.x * gridDim.y * gridDim.z * 256;
    const int n4 = (W * HH) / 4;
    for (int i = bid * 256 + t; i < n4; i += nthr) {
      float4 a = ((const float4*)Xr)[i];
      float4 b = ((const float4*)St)[i];
      gm += fabsf(b.x - a.x) + fabsf(b.y - a.y)
          + fabsf(b.z - a.z) + fabsf(b.w - a.w);
    }
    for (int i = bid * 256 + t; i < 384 * 384; i += nthr) {
      int si = i / 384, sj = i - si * 384;
      int id = si * 8 * W + sj * 8;
      gm += fabsf(T[id] - Gnn[id]) * Mp[id];
    }
  }

  reduce_add(tvl, &acc[1]);
  reduce_add(hl, &acc[3]);
  reduce_add(gm, &acc[0]);
}

// ---- combine ---------------------------------------------------------------
__global__ void finalize_kernel(const double* acc, float* out) {
  out[0] = (float)(acc[0] + acc[2] + 0.1 * acc[1] + 0.5 * acc[3]);
}

extern "C" void kernel_launch(void* const* d_in, const int* in_sizes, int n_in,
                              void* d_out, int out_size, void* d_ws, size_t ws_size,
                              hipStream_t stream) {
  const float* xraw = (const float*)d_in[0];   // outputGNNraw
  const float* gnn  = (const float*)d_in[1];   // outputGNN
  const float* lr   = (const float*)d_in[2];   // outputLR
  const float* st   = (const float*)d_in[3];   // smoothedTarget
  const float* tg   = (const float*)d_in[4];   // targets
  const float* mp   = (const float*)d_in[5];   // map
  float* out = (float*)d_out;

  double* acc = (double*)d_ws;
  hipMemsetAsync(d_ws, 0, 32, stream);   // zero the 4 f64 accumulators

  // separable Hessian-of-Gaussian taps (sigma=1, t = -6..6):
  //   Gxx[i,j] = bb(i)*a(j); Gyy[i,j] = a(i)*bb(j); Gxy[i,j] = m(i)*n(j)
  HessTaps tp;
  const double PI2 = 6.283185307179586476925287;
  for (int k = 0; k < 13; ++k) {
    double tt = (double)(k - 6);
    double g = exp(-0.5 * tt * tt);
    tp.a[k]  = (float)((tt * tt - 1.0) * g / PI2);
    tp.bb[k] = (float)g;
    tp.m[k]  = (float)(tt * g / PI2);
    tp.n[k]  = (float)(tt * g);
  }
  // pair tables for the packed H pass: p[j] = {tap[j], tap[j-1]}, 0-padded
  for (int j = 0; j < 14; ++j) {
    tp.pa[j]  = (f2){ (j < 13) ? tp.a[j]  : 0.f, (j >= 1) ? tp.a[j - 1]  : 0.f };
    tp.pbb[j] = (f2){ (j < 13) ? tp.bb[j] : 0.f, (j >= 1) ? tp.bb[j - 1] : 0.f };
    tp.pm[j]  = (f2){ (j < 13) ? tp.m[j]  : 0.f, (j >= 1) ? tp.m[j - 1]  : 0.f };
    tp.pn[j]  = (f2){ (j < 13) ? tp.n[j]  : 0.f, (j >= 1) ? tp.n[j - 1]  : 0.f };
  }

  // grid: 48 x-tiles (48*64=3072 cols), 55 y-tiles (55*56=3080 >= 3072 rows,
  // per-row masks handle the overhang), z = {GNN, LR}
  hess_kernel<<<dim3(48, 55, 2), 256, 0, stream>>>(gnn, lr, tg, xraw, st, mp,
                                                   acc, tp);

  finalize_kernel<<<1, 1, 0, stream>>>(acc, out);
}